// Round 1
// baseline (45.821 us; speedup 1.0000x reference)
//
#include <hip/hip_runtime.h>
#include <hip/hip_bf16.h>
#include <hip/hip_fp16.h>

// Problem constants (match reference)
#define NRAYS 1048576
#define NV 32
#define ND 32
#define NF 6
#define NK 13  // 2F+1

typedef _Float16 h2 __attribute__((ext_vector_type(2)));

#if __has_builtin(__builtin_amdgcn_fdot2)
__device__ __forceinline__ float fdot2acc(h2 a, h2 b, float c) {
    return __builtin_amdgcn_fdot2(a, b, c, false);
}
#else
__device__ __forceinline__ float fdot2acc(h2 a, h2 b, float c) {
    return c + (float)a.x * (float)b.x + (float)a.y * (float)b.y;
}
#endif

// 8 threads per ray: thread q owns d = 4q..4q+3.
// LDS weight layout: [V][7 k-pairs][D][2] halves = 14336 halves = 28672 B.
//   half index = v*448 + (k>>1)*64 + d*2 + (k&1)
// ds_read_b128 per k-pair: addr = v*896B + i*128B + q*16B.
//   v-stride 896B == 0 mod 128B -> vid drops out of bank index;
//   q=0..7 covers all 32 banks exactly once per ray-group.
__global__ __launch_bounds__(256, 4) void VideoEmbedding_kernel(
    const float* __restrict__ times,
    const int* __restrict__ vids,
    const float* __restrict__ weights,
    float* __restrict__ out)
{
    __shared__ _Float16 wl[NV * 7 * ND * 2];  // 28672 B

    const int tid = threadIdx.x;

    // Zero the k=13 pad slots (pair i=6, odd half)
    for (int j = tid; j < NV * ND; j += 256) {
        int v = j >> 5, d = j & 31;
        wl[v * 448 + 6 * 64 + d * 2 + 1] = (_Float16)0.f;
    }
    // Fill k = 0..12 (disjoint from pad slots, so one sync suffices)
    for (int j = tid; j < NV * ND * NK; j += 256) {
        int v = j / (ND * NK);
        int r = j - v * (ND * NK);
        int d = r / NK;
        int k = r - d * NK;
        wl[v * 448 + (k >> 1) * 64 + d * 2 + (k & 1)] = (_Float16)weights[j];
    }
    __syncthreads();

    const int q = tid & 7;
    const int slot0 = ((blockIdx.x * 256) + tid) >> 3;
    const int nslots = (gridDim.x * 256) >> 3;

    for (int ray = slot0; ray < NRAYS; ray += nslots) {
        const float t = times[ray];
        const int vid = vids[ray];

        // basis = [1, sin(2^j pi t) j=0..5, cos(2^j pi t) j=0..5]
        float s, c;
        sincospif(t, &s, &c);
        float basis[14];
        basis[0] = 1.f;
        basis[1] = s;
        basis[7] = c;
        float sj = s, cj = c;
#pragma unroll
        for (int j = 1; j < NF; ++j) {
            float s2 = 2.f * sj * cj;
            float c2 = 1.f - 2.f * sj * sj;
            sj = s2; cj = c2;
            basis[1 + j] = sj;
            basis[7 + j] = cj;
        }
        basis[13] = 0.f;  // pad

        h2 bp[7];
#pragma unroll
        for (int i = 0; i < 7; ++i) {
            h2 p;
            p.x = (_Float16)basis[2 * i];
            p.y = (_Float16)basis[2 * i + 1];
            bp[i] = p;
        }

        const unsigned base = (unsigned)vid * 448u + (unsigned)q * 8u;
        float a0 = 0.f, a1 = 0.f, a2 = 0.f, a3 = 0.f;
#pragma unroll
        for (int i = 0; i < 7; ++i) {
            uint4 w = *reinterpret_cast<const uint4*>(&wl[base + i * 64]);
            h2 w0 = __builtin_bit_cast(h2, w.x);
            h2 w1 = __builtin_bit_cast(h2, w.y);
            h2 w2 = __builtin_bit_cast(h2, w.z);
            h2 w3 = __builtin_bit_cast(h2, w.w);
            a0 = fdot2acc(w0, bp[i], a0);
            a1 = fdot2acc(w1, bp[i], a1);
            a2 = fdot2acc(w2, bp[i], a2);
            a3 = fdot2acc(w3, bp[i], a3);
        }

        float4 res;
        res.x = a0; res.y = a1; res.z = a2; res.w = a3;
        reinterpret_cast<float4*>(out)[ray * 8 + q] = res;
    }
}

extern "C" void kernel_launch(void* const* d_in, const int* in_sizes, int n_in,
                              void* d_out, int out_size, void* d_ws, size_t ws_size,
                              hipStream_t stream) {
    const float* times = (const float*)d_in[0];
    const int* vids = (const int*)d_in[1];
    const float* weights = (const float*)d_in[2];
    float* out = (float*)d_out;

    // 1280 blocks = 5 blocks/CU (LDS-limited at 28672 B/block), grid-stride.
    dim3 grid(1280), block(256);
    hipLaunchKernelGGL(VideoEmbedding_kernel, grid, block, 0, stream,
                       times, vids, weights, out);
}

// Round 3
// 39.229 us; speedup vs baseline: 1.1680x; 1.1680x over previous
//
#include <hip/hip_runtime.h>
#include <hip/hip_fp16.h>

// Problem constants (match reference)
#define NRAYS 1048576
#define NV 32
#define ND 32
#define NF 6
#define NK 13  // 2F+1

typedef _Float16 h2 __attribute__((ext_vector_type(2)));
typedef float f4 __attribute__((ext_vector_type(4)));

__device__ __forceinline__ float fdot2acc(h2 a, h2 b, float c) {
#if __has_builtin(__builtin_amdgcn_fdot2)
    return __builtin_amdgcn_fdot2(a, b, c, false);
#else
    return c + (float)a.x * (float)b.x + (float)a.y * (float)b.y;
#endif
}

__device__ __forceinline__ h2 pack2(float a, float b) {
#if __has_builtin(__builtin_amdgcn_cvt_pkrtz)
    return __builtin_bit_cast(h2, __builtin_amdgcn_cvt_pkrtz(a, b));
#else
    h2 r; r.x = (_Float16)a; r.y = (_Float16)b; return r;
#endif
}

// sin/cos of (2*pi*rev) via raw HW transcendental (input in revolutions)
__device__ __forceinline__ float hwsin(float rev) {
#if __has_builtin(__builtin_amdgcn_sinf)
    return __builtin_amdgcn_sinf(rev);
#else
    return __sinf(6.28318530717958647692f * rev);
#endif
}
__device__ __forceinline__ float hwcos(float rev) {
#if __has_builtin(__builtin_amdgcn_cosf)
    return __builtin_amdgcn_cosf(rev);
#else
    return __cosf(6.28318530717958647692f * rev);
#endif
}

// 8 threads per ray: thread q owns d = 4q..4q+3.
// LDS weight layout: [V][7 k-pairs][D][2] halves = 14336 halves = 28672 B.
//   half index = v*448 + (k>>1)*64 + d*2 + (k&1)
// ds_read_b128 per k-pair: addr = v*896B + i*128B + q*16B.
//   v-stride 896B == 0 mod 128B -> vid drops out of bank index;
//   q=0..7 covers all 32 banks exactly once per ray-group => conflict-free.
__global__ __launch_bounds__(256, 5) void VideoEmbedding_kernel(
    const float* __restrict__ times,
    const int* __restrict__ vids,
    const float* __restrict__ weights,
    float* __restrict__ out)
{
    __shared__ _Float16 wl[NV * 7 * ND * 2];  // 28672 B -> 5 blocks/CU

    const int tid = threadIdx.x;

    // Zero the k=13 pad slots (pair i=6, odd half)
    for (int j = tid; j < NV * ND; j += 256) {
        int v = j >> 5, d = j & 31;
        wl[v * 448 + 6 * 64 + d * 2 + 1] = (_Float16)0.f;
    }
    // Fill k = 0..12 (disjoint from pad slots, so one sync suffices)
    for (int j = tid; j < NV * ND * NK; j += 256) {
        int v = j / (ND * NK);
        int r = j - v * (ND * NK);
        int d = r / NK;
        int k = r - d * NK;
        wl[v * 448 + (k >> 1) * 64 + d * 2 + (k & 1)] = (_Float16)weights[j];
    }
    __syncthreads();

    const int q = tid & 7;
    int ray = ((blockIdx.x * 256) + tid) >> 3;
    const int nslots = (gridDim.x * 256) >> 3;

    // software pipeline: t/vid for current iteration loaded one iter ahead
    float t = 0.f;
    int vid = 0;
    if (ray < NRAYS) {
        t = times[ray];
        vid = vids[ray];
    }

    while (ray < NRAYS) {
        const int nray = ray + nslots;
        float tn = 0.f;
        int vidn = 0;
        if (nray < NRAYS) {
            tn = times[nray];
            vidn = vids[nray];
        }

        // basis = [1, sin(2^j pi t), cos(2^j pi t)] j=0..5
        // revolutions: 2^j*pi*t = 2*pi*(t*2^(j-1)); max |rev| = 16
        float sv[NF], cv[NF];
        float rev = 0.5f * t;
#pragma unroll
        for (int j = 0; j < NF; ++j) {
            sv[j] = hwsin(rev);
            cv[j] = hwcos(rev);
            rev += rev;
        }

        h2 bp[7];
        bp[0] = pack2(1.0f, sv[0]);
        bp[1] = pack2(sv[1], sv[2]);
        bp[2] = pack2(sv[3], sv[4]);
        bp[3] = pack2(sv[5], cv[0]);
        bp[4] = pack2(cv[1], cv[2]);
        bp[5] = pack2(cv[3], cv[4]);
        bp[6] = pack2(cv[5], 0.0f);  // pad half must be 0

        const unsigned base = (unsigned)vid * 448u + (unsigned)q * 8u;
        uint4 w[7];
#pragma unroll
        for (int i = 0; i < 7; ++i)
            w[i] = *reinterpret_cast<const uint4*>(&wl[base + i * 64]);

        float a0 = 0.f, a1 = 0.f, a2 = 0.f, a3 = 0.f;
#pragma unroll
        for (int i = 0; i < 7; ++i) {
            h2 w0 = __builtin_bit_cast(h2, w[i].x);
            h2 w1 = __builtin_bit_cast(h2, w[i].y);
            h2 w2 = __builtin_bit_cast(h2, w[i].z);
            h2 w3 = __builtin_bit_cast(h2, w[i].w);
            a0 = fdot2acc(w0, bp[i], a0);
            a1 = fdot2acc(w1, bp[i], a1);
            a2 = fdot2acc(w2, bp[i], a2);
            a3 = fdot2acc(w3, bp[i], a3);
        }

        f4 res;
        res.x = a0; res.y = a1; res.z = a2; res.w = a3;
        __builtin_nontemporal_store(res, reinterpret_cast<f4*>(out) + (size_t)ray * 8 + q);

        ray = nray;
        t = tn;
        vid = vidn;
    }
}

extern "C" void kernel_launch(void* const* d_in, const int* in_sizes, int n_in,
                              void* d_out, int out_size, void* d_ws, size_t ws_size,
                              hipStream_t stream) {
    const float* times = (const float*)d_in[0];
    const int* vids = (const int*)d_in[1];
    const float* weights = (const float*)d_in[2];
    float* out = (float*)d_out;

    // 1280 blocks = 5 blocks/CU (LDS-limited at 28672 B/block), grid-stride.
    dim3 grid(1280), block(256);
    hipLaunchKernelGGL(VideoEmbedding_kernel, grid, block, 0, stream,
                       times, vids, weights, out);
}

// Round 4
// 37.594 us; speedup vs baseline: 1.2188x; 1.0435x over previous
//
#include <hip/hip_runtime.h>
#include <hip/hip_fp16.h>

// Problem constants (match reference)
#define NRAYS 1048576
#define NV 32
#define ND 32
#define NF 6
#define NK 13  // 2F+1

typedef _Float16 h2 __attribute__((ext_vector_type(2)));
typedef float f4 __attribute__((ext_vector_type(4)));

__device__ __forceinline__ float fdot2acc(h2 a, h2 b, float c) {
#if __has_builtin(__builtin_amdgcn_fdot2)
    return __builtin_amdgcn_fdot2(a, b, c, false);
#else
    return c + (float)a.x * (float)b.x + (float)a.y * (float)b.y;
#endif
}

__device__ __forceinline__ h2 pack2(float a, float b) {
#if __has_builtin(__builtin_amdgcn_cvt_pkrtz)
    return __builtin_bit_cast(h2, __builtin_amdgcn_cvt_pkrtz(a, b));
#else
    h2 r; r.x = (_Float16)a; r.y = (_Float16)b; return r;
#endif
}

__device__ __forceinline__ float hwsin(float rev) {
#if __has_builtin(__builtin_amdgcn_sinf)
    return __builtin_amdgcn_sinf(rev);
#else
    return __sinf(6.28318530717958647692f * rev);
#endif
}
__device__ __forceinline__ float hwcos(float rev) {
#if __has_builtin(__builtin_amdgcn_cosf)
    return __builtin_amdgcn_cosf(rev);
#else
    return __cosf(6.28318530717958647692f * rev);
#endif
}

// ---------------------------------------------------------------------------
// Kernel A: pack f32 weights [V][D][K] into the f16 LDS image in d_ws.
// Image layout (halves): idx = v*448 + i*64 + d*2 + (k&1), i = k>>1, 28672 B.
// One uint (h2 pair) per thread: 7168 uints.
__global__ void pack_weights_kernel(const float* __restrict__ weights,
                                    unsigned* __restrict__ wpack)
{
    int j = blockIdx.x * 256 + threadIdx.x;  // 0 .. 7167
    if (j >= NV * 7 * ND) return;
    int v = j >> 8;            // /224? careful: 7*32 = 224 per v
    v = j / 224;
    int r = j - v * 224;
    int i = r >> 5;            // k-pair 0..6
    int d = r & 31;
    float w0 = weights[v * (ND * NK) + d * NK + 2 * i];
    float w1 = (2 * i + 1 < NK) ? weights[v * (ND * NK) + d * NK + 2 * i + 1] : 0.f;
    h2 p = pack2(w0, w1);
    wpack[v * 224 + i * 32 + d] = __builtin_bit_cast(unsigned, p);
}

// ---------------------------------------------------------------------------
// Main kernel. 8 threads per ray: thread q owns d = 4q..4q+3.
// LDS = linear copy of the packed image; per-ray read:
//   ds_read_b128 at v*896B + i*128B + q*16B  (v-stride 896 == 0 mod 128
//   -> bank index independent of vid; q covers all 32 banks).
__global__ __launch_bounds__(256, 5) void VideoEmbedding_kernel(
    const float* __restrict__ times,
    const int* __restrict__ vids,
    const unsigned* __restrict__ wpack,
    float* __restrict__ out)
{
    __shared__ _Float16 wl[NV * 7 * ND * 2];  // 28672 B -> 5 blocks/CU

    const int tid = threadIdx.x;

    // Stage the pre-packed image: 7 x uint4 per thread, fully coalesced.
    {
        const uint4* src = reinterpret_cast<const uint4*>(wpack);
        uint4* dst = reinterpret_cast<uint4*>(wl);
#pragma unroll
        for (int j = 0; j < 7; ++j)
            dst[tid + j * 256] = src[tid + j * 256];
    }
    __syncthreads();

    const int q = tid & 7;
    const int nslots = (gridDim.x * 256) >> 3;
    int ray = ((blockIdx.x * 256) + tid) >> 3;

    // prefetch depth 2
    int rA = ray < NRAYS ? ray : 0;
    int rB = ray + nslots < NRAYS ? ray + nslots : 0;
    float tA = times[rA], tB = times[rB];
    int vA = vids[rA], vB = vids[rB];

    while (ray < NRAYS) {
        const int ray2 = ray + 2 * nslots;
        const int rC = ray2 < NRAYS ? ray2 : 0;
        const float tC = times[rC];
        const int vC = vids[rC];

        // basis = [1, sin(2^j pi t), cos(2^j pi t)] j=0..5
        // revolutions: 2^j*pi*t = 2*pi*(t*2^(j-1)); max |rev| = 16
        float sv[NF], cv[NF];
        float rev = 0.5f * tA;
#pragma unroll
        for (int j = 0; j < NF; ++j) {
            sv[j] = hwsin(rev);
            cv[j] = hwcos(rev);
            rev += rev;
        }

        h2 bp[7];
        bp[0] = pack2(1.0f, sv[0]);
        bp[1] = pack2(sv[1], sv[2]);
        bp[2] = pack2(sv[3], sv[4]);
        bp[3] = pack2(sv[5], cv[0]);
        bp[4] = pack2(cv[1], cv[2]);
        bp[5] = pack2(cv[3], cv[4]);
        bp[6] = pack2(cv[5], 0.0f);  // pad half must be 0

        const unsigned base = (unsigned)vA * 448u + (unsigned)q * 8u;
        uint4 w[7];
#pragma unroll
        for (int i = 0; i < 7; ++i)
            w[i] = *reinterpret_cast<const uint4*>(&wl[base + i * 64]);

        float a0 = 0.f, a1 = 0.f, a2 = 0.f, a3 = 0.f;
#pragma unroll
        for (int i = 0; i < 7; ++i) {
            a0 = fdot2acc(__builtin_bit_cast(h2, w[i].x), bp[i], a0);
            a1 = fdot2acc(__builtin_bit_cast(h2, w[i].y), bp[i], a1);
            a2 = fdot2acc(__builtin_bit_cast(h2, w[i].z), bp[i], a2);
            a3 = fdot2acc(__builtin_bit_cast(h2, w[i].w), bp[i], a3);
        }

        f4 res;
        res.x = a0; res.y = a1; res.z = a2; res.w = a3;
        reinterpret_cast<f4*>(out)[(size_t)ray * 8 + q] = res;

        ray += nslots;
        tA = tB; vA = vB;
        tB = tC; vB = vC;
    }
}

extern "C" void kernel_launch(void* const* d_in, const int* in_sizes, int n_in,
                              void* d_out, int out_size, void* d_ws, size_t ws_size,
                              hipStream_t stream) {
    const float* times = (const float*)d_in[0];
    const int* vids = (const int*)d_in[1];
    const float* weights = (const float*)d_in[2];
    float* out = (float*)d_out;
    unsigned* wpack = (unsigned*)d_ws;

    hipLaunchKernelGGL(pack_weights_kernel, dim3(28), dim3(256), 0, stream,
                       weights, wpack);
    // 1280 blocks = 5 blocks/CU (LDS-limited at 28672 B/block), grid-stride.
    hipLaunchKernelGGL(VideoEmbedding_kernel, dim3(1280), dim3(256), 0, stream,
                       times, vids, wpack, out);
}

// Round 5
// 36.651 us; speedup vs baseline: 1.2502x; 1.0257x over previous
//
#include <hip/hip_runtime.h>
#include <hip/hip_fp16.h>

// Problem constants (match reference)
#define NRAYS 1048576
#define NV 32
#define ND 32
#define NF 6
#define NK 13  // 2F+1

typedef _Float16 h2 __attribute__((ext_vector_type(2)));
typedef float f4 __attribute__((ext_vector_type(4)));

__device__ __forceinline__ float fdot2acc(h2 a, h2 b, float c) {
#if __has_builtin(__builtin_amdgcn_fdot2)
    return __builtin_amdgcn_fdot2(a, b, c, false);
#else
    return c + (float)a.x * (float)b.x + (float)a.y * (float)b.y;
#endif
}

__device__ __forceinline__ h2 pack2(float a, float b) {
#if __has_builtin(__builtin_amdgcn_cvt_pkrtz)
    return __builtin_bit_cast(h2, __builtin_amdgcn_cvt_pkrtz(a, b));
#else
    h2 r; r.x = (_Float16)a; r.y = (_Float16)b; return r;
#endif
}

__device__ __forceinline__ float hwsin(float rev) {
#if __has_builtin(__builtin_amdgcn_sinf)
    return __builtin_amdgcn_sinf(rev);
#else
    return __sinf(6.28318530717958647692f * rev);
#endif
}
__device__ __forceinline__ float hwcos(float rev) {
#if __has_builtin(__builtin_amdgcn_cosf)
    return __builtin_amdgcn_cosf(rev);
#else
    return __cosf(6.28318530717958647692f * rev);
#endif
}

// ---------------------------------------------------------------------------
// Kernel A: pack f32 weights [V][D][K] into the f16 image in d_ws, with the
// d-quad chunks XOR-swizzled by (v&7) inside each 128B row so that the LDS
// bank footprint depends on vid (kills the systematic 8-way conflict).
// Image (dwords): idx = v*224 + i*32 + pos*4 + e, where the chunk at `pos`
// holds d-quad q = pos ^ (v&7); dword e -> d = 4q+e, halves (k=2i, 2i+1).
__global__ void pack_weights_kernel(const float* __restrict__ weights,
                                    unsigned* __restrict__ wpack)
{
    int j = blockIdx.x * 256 + threadIdx.x;  // 0 .. 7167 (dwords)
    if (j >= NV * 7 * 32) return;
    int v = j / 224;
    int r = j - v * 224;
    int i = r >> 5;          // k-pair 0..6
    int c = r & 31;          // dword within 128B row
    int pos = c >> 2;        // chunk position 0..7
    int e = c & 3;           // dword within chunk
    int q = pos ^ (v & 7);   // d-quad stored at this position
    int d = 4 * q + e;
    float w0 = weights[v * (ND * NK) + d * NK + 2 * i];
    float w1 = (2 * i + 1 < NK) ? weights[v * (ND * NK) + d * NK + 2 * i + 1] : 0.f;
    h2 p = pack2(w0, w1);
    wpack[j] = __builtin_bit_cast(unsigned, p);
}

// ---------------------------------------------------------------------------
// Main kernel. 8 threads per ray: thread q owns d = 4q..4q+3.
// Per-ray read: ds_read_b128 at v*896B + i*128B + (q^(v&7))*16B.
__global__ __launch_bounds__(256, 5) void VideoEmbedding_kernel(
    const float* __restrict__ times,
    const int* __restrict__ vids,
    const unsigned* __restrict__ wpack,
    float* __restrict__ out)
{
    __shared__ _Float16 wl[NV * 7 * ND * 2];  // 28672 B -> 5 blocks/CU

    const int tid = threadIdx.x;

    // Stage the pre-packed image: 7 x uint4 per thread, fully coalesced.
    {
        const uint4* src = reinterpret_cast<const uint4*>(wpack);
        uint4* dst = reinterpret_cast<uint4*>(wl);
#pragma unroll
        for (int j = 0; j < 7; ++j)
            dst[tid + j * 256] = src[tid + j * 256];
    }
    __syncthreads();

    const int q = tid & 7;
    const int nslots = (gridDim.x * 256) >> 3;
    int ray = ((blockIdx.x * 256) + tid) >> 3;

    // prefetch depth 2
    int rA = ray < NRAYS ? ray : 0;
    int rB = ray + nslots < NRAYS ? ray + nslots : 0;
    float tA = times[rA], tB = times[rB];
    int vA = vids[rA], vB = vids[rB];

    while (ray < NRAYS) {
        const int ray2 = ray + 2 * nslots;
        const int rC = ray2 < NRAYS ? ray2 : 0;
        const float tC = times[rC];
        const int vC = vids[rC];

        // basis: s_j = sin(2^j pi t), c_j = cos(2^j pi t), j=0..5.
        // seed with HW trans (input in revolutions: 0.5t), then double-angle.
        float sv[NF], cv[NF];
        sv[0] = hwsin(0.5f * tA);
        cv[0] = hwcos(0.5f * tA);
#pragma unroll
        for (int j = 1; j < NF; ++j) {
            float sj = sv[j - 1], cj = cv[j - 1];
            sv[j] = 2.f * sj * cj;
            cv[j] = fmaf(-2.f * sj, sj, 1.f);
        }

        h2 bp[7];
        bp[0] = pack2(1.0f, sv[0]);
        bp[1] = pack2(sv[1], sv[2]);
        bp[2] = pack2(sv[3], sv[4]);
        bp[3] = pack2(sv[5], cv[0]);
        bp[4] = pack2(cv[1], cv[2]);
        bp[5] = pack2(cv[3], cv[4]);
        bp[6] = pack2(cv[5], 0.0f);  // pad half must be 0

        const unsigned pos = (unsigned)(q ^ (vA & 7));
        const unsigned base = (unsigned)vA * 448u + pos * 8u;  // half index
        uint4 w[7];
#pragma unroll
        for (int i = 0; i < 7; ++i)
            w[i] = *reinterpret_cast<const uint4*>(&wl[base + i * 64]);

        float a0 = 0.f, a1 = 0.f, a2 = 0.f, a3 = 0.f;
#pragma unroll
        for (int i = 0; i < 7; ++i) {
            a0 = fdot2acc(__builtin_bit_cast(h2, w[i].x), bp[i], a0);
            a1 = fdot2acc(__builtin_bit_cast(h2, w[i].y), bp[i], a1);
            a2 = fdot2acc(__builtin_bit_cast(h2, w[i].z), bp[i], a2);
            a3 = fdot2acc(__builtin_bit_cast(h2, w[i].w), bp[i], a3);
        }

        f4 res;
        res.x = a0; res.y = a1; res.z = a2; res.w = a3;
        reinterpret_cast<f4*>(out)[(size_t)ray * 8 + q] = res;

        ray += nslots;
        tA = tB; vA = vB;
        tB = tC; vB = vC;
    }
}

extern "C" void kernel_launch(void* const* d_in, const int* in_sizes, int n_in,
                              void* d_out, int out_size, void* d_ws, size_t ws_size,
                              hipStream_t stream) {
    const float* times = (const float*)d_in[0];
    const int* vids = (const int*)d_in[1];
    const float* weights = (const float*)d_in[2];
    float* out = (float*)d_out;
    unsigned* wpack = (unsigned*)d_ws;

    hipLaunchKernelGGL(pack_weights_kernel, dim3(28), dim3(256), 0, stream,
                       weights, wpack);
    // 1280 blocks = 5 blocks/CU (LDS-limited at 28672 B/block), grid-stride.
    hipLaunchKernelGGL(VideoEmbedding_kernel, dim3(1280), dim3(256), 0, stream,
                       times, vids, wpack, out);
}